// Round 1
// baseline (238.791 us; speedup 1.0000x reference)
//
#include <hip/hip_runtime.h>

// RIDE 4-way self-distillation KL loss, N x C (C=7), fp32.
// loss = mean_n [ (kl2+kl3+kl4) * mean(T^2) / 3 ],
// kl_j = (1/7) * sum_c q_c (logq_c - logsoftmax(z_j)_c), z = x * (1/T).
// Using sum(q)=1:  sum_c q_c*lp_j,c = dot(q,z_j) - (m_j + log S_j).
// targets input is dead. Pure HBM-bound stream: 235 MB -> ~37 us floor.

struct RideConsts {
    float invT[7];
    float scale;   // mean(T^2) / (3*N)
};

__global__ __launch_bounds__(256) void ride_kernel(
    const float* __restrict__ x1, const float* __restrict__ x2,
    const float* __restrict__ x3, const float* __restrict__ x4,
    float* __restrict__ out, RideConsts cst, int nthreads)
{
    const int tid = blockIdx.x * 256 + threadIdx.x;
    float cost_sum = 0.0f;

    if (tid < nthreads) {
        // Each thread owns 4 consecutive rows = 28 floats = 7 float4 per array.
        const long long base = (long long)tid * 28;

        float q[28];      // teacher probs for 4 rows
        float qlogq[4];   // sum_c q*logq per row

        // ---- array 1: teacher ----
        {
            float a[28];
            const float4* p = reinterpret_cast<const float4*>(x1 + base);
#pragma unroll
            for (int k = 0; k < 7; ++k) {
                float4 v = p[k];
                a[4*k+0] = v.x; a[4*k+1] = v.y; a[4*k+2] = v.z; a[4*k+3] = v.w;
            }
#pragma unroll
            for (int r = 0; r < 4; ++r) {
                float z[7];
                float m = -1e30f;
#pragma unroll
                for (int c = 0; c < 7; ++c) {
                    z[c] = a[7*r+c] * cst.invT[c];
                    m = fmaxf(m, z[c]);
                }
                float S = 0.0f;
#pragma unroll
                for (int c = 0; c < 7; ++c) {
                    float e = __expf(z[c] - m);
                    q[7*r+c] = e;
                    S += e;
                }
                const float invS = 1.0f / S;
                const float logS = __logf(S);
                float s_ql = 0.0f;
#pragma unroll
                for (int c = 0; c < 7; ++c) {
                    const float qq = q[7*r+c] * invS;
                    q[7*r+c] = qq;
                    s_ql += qq * (z[c] - m - logS);
                }
                qlogq[r] = s_ql;
            }
        }

        // ---- arrays 2..4: students ----
        const float* arrs[3] = {x2, x3, x4};
#pragma unroll
        for (int j = 0; j < 3; ++j) {
            float a[28];
            const float4* p = reinterpret_cast<const float4*>(arrs[j] + base);
#pragma unroll
            for (int k = 0; k < 7; ++k) {
                float4 v = p[k];
                a[4*k+0] = v.x; a[4*k+1] = v.y; a[4*k+2] = v.z; a[4*k+3] = v.w;
            }
#pragma unroll
            for (int r = 0; r < 4; ++r) {
                float z[7];
                float m = -1e30f;
#pragma unroll
                for (int c = 0; c < 7; ++c) {
                    z[c] = a[7*r+c] * cst.invT[c];
                    m = fmaxf(m, z[c]);
                }
                float S = 0.0f, dot = 0.0f;
#pragma unroll
                for (int c = 0; c < 7; ++c) {
                    S   += __expf(z[c] - m);
                    dot += q[7*r+c] * z[c];
                }
                const float lse = m + __logf(S);
                // kl_j*7 for this row = qlogq - (dot - lse)
                cost_sum += qlogq[r] - dot + lse;
            }
        }
    }

    cost_sum *= (1.0f / 7.0f);   // the mean-over-C

    // wave (64) reduction
#pragma unroll
    for (int off = 32; off > 0; off >>= 1)
        cost_sum += __shfl_down(cost_sum, off, 64);

    __shared__ float red[4];
    const int wave = threadIdx.x >> 6;
    const int lane = threadIdx.x & 63;
    if (lane == 0) red[wave] = cost_sum;
    __syncthreads();
    if (threadIdx.x == 0) {
        atomicAdd(out, (red[0] + red[1] + red[2] + red[3]) * cst.scale);
    }
}

extern "C" void kernel_launch(void* const* d_in, const int* in_sizes, int n_in,
                              void* d_out, int out_size, void* d_ws, size_t ws_size,
                              hipStream_t stream)
{
    const float* x1 = (const float*)d_in[0];
    const float* x2 = (const float*)d_in[1];
    const float* x3 = (const float*)d_in[2];
    const float* x4 = (const float*)d_in[3];
    // d_in[4] = targets: dead input, never read.

    const int N = in_sizes[0] / 7;

    // Reproduce _temperature() exactly (double math, cast to fp32 like jnp).
    RideConsts cst;
    {
        const double cls[7] = {705, 717, 281, 4772, 1982, 1290, 2524};
        double sum = 0.0;
        for (int c = 0; c < 7; ++c) sum += cls[c];
        double w[7], wmax = 0.0;
        for (int c = 0; c < 7; ++c) {
            const double p = cls[c] / sum;
            w[c] = 7.0 * p * 0.015 + 1.0 - 0.015;
            if (w[c] > wmax) wmax = w[c];
        }
        double mT2 = 0.0;
        for (int c = 0; c < 7; ++c) {
            const float T = (float)(1.5 * (w[c] / wmax));
            cst.invT[c] = 1.0f / T;
            mT2 += (double)T * (double)T;
        }
        mT2 /= 7.0;
        cst.scale = (float)(mT2 / (3.0 * (double)N));
    }

    // Output accumulator must start at 0 (harness poisons with 0xAA).
    hipMemsetAsync(d_out, 0, sizeof(float), stream);

    const int nthreads = N / 4;                  // N = 2097152, divisible by 4
    const int blocks = (nthreads + 255) / 256;
    ride_kernel<<<blocks, 256, 0, stream>>>(x1, x2, x3, x4, (float*)d_out,
                                            cst, nthreads);
}

// Round 2
// 232.885 us; speedup vs baseline: 1.0254x; 1.0254x over previous
//
#include <hip/hip_runtime.h>

// RIDE 4-way self-distillation KL loss, N x C (C=7), fp32. Scalar output.
// R1 analysis: latency-bound (32 waves x 7 loads x 16B = 3.6 KB/CU in flight
// -> 2.4 TB/s by Little's law; measured 2.5 TB/s). Fix: global_load_lds async
// staging (no VGPR cost) with double-buffered LDS -> 57 KB/CU in flight.
//
// Per block (256 threads = 4 waves): chunk = 256 rows. Wave w DMAs array w's
// 7168 B chunk as 7 wave-wide 1 KB global_load_lds ops. Thread t computes
// row t from LDS (stride-7-word reads: conflict-free, 2 lanes/bank).

struct RideConsts {
    float invT[7];
    float scale;   // mean(T^2) / (3*N)
};

#define GLD_LDS16(g, l)                                           \
    __builtin_amdgcn_global_load_lds(                             \
        (const __attribute__((address_space(1))) void*)(g),       \
        (__attribute__((address_space(3))) void*)(l), 16, 0, 0)

__global__ __launch_bounds__(256) void ride_kernel(
    const float* __restrict__ x1, const float* __restrict__ x2,
    const float* __restrict__ x3, const float* __restrict__ x4,
    float* __restrict__ out, RideConsts cst, int chunksPerBlock)
{
    // [buf][array][256 rows * 7 floats] = 2*4*1792*4 B = 57344 B
    __shared__ float lds[2][4][1792];
    __shared__ float red[4];

    const int t    = threadIdx.x;
    const int w    = t >> 6;     // wave id 0..3 -> which array this wave DMAs
    const int lane = t & 63;

    const float* xw = (w == 0) ? x1 : (w == 1) ? x2 : (w == 2) ? x3 : x4;

    const long long chunk0 = (long long)blockIdx.x * chunksPerBlock;

    // Prologue: DMA chunk0 into buffer 0. 448 float4 per array; lane i takes
    // float4 (k*64+i); LDS dest is wave-uniform base + lane*16 (HW rule).
    {
        const float4* gp = (const float4*)xw + chunk0 * 448 + lane;
#pragma unroll
        for (int k = 0; k < 7; ++k)
            GLD_LDS16(gp + k * 64, &lds[0][w][k * 256]);
    }
    __syncthreads();   // drains vmcnt(0): buffer 0 complete for all waves

    float cost_sum = 0.0f;

    for (int it = 0; it < chunksPerBlock; ++it) {
        const int cur = it & 1;

        // Prefetch next chunk into the other buffer; stays in flight during
        // compute, drained by the __syncthreads at loop bottom.
        if (it + 1 < chunksPerBlock) {
            const float4* gp = (const float4*)xw + (chunk0 + it + 1) * 448 + lane;
            float* dst = &lds[cur ^ 1][w][0];
#pragma unroll
            for (int k = 0; k < 7; ++k)
                GLD_LDS16(gp + k * 64, dst + k * 256);
        }

        // ---- compute: thread t owns row t of this chunk ----
        float z0[7], q[7];
        float qlogq;
        {
            const float* r = &lds[cur][0][t * 7];
            float m = -1e30f;
#pragma unroll
            for (int c = 0; c < 7; ++c) {
                z0[c] = r[c] * cst.invT[c];
                m = fmaxf(m, z0[c]);
            }
            float S = 0.0f;
#pragma unroll
            for (int c = 0; c < 7; ++c) {
                float e = __expf(z0[c] - m);
                q[c] = e;
                S += e;
            }
            const float invS = 1.0f / S;
            const float logS = __logf(S);
            float s_ql = 0.0f;
#pragma unroll
            for (int c = 0; c < 7; ++c) {
                q[c] *= invS;
                s_ql += q[c] * (z0[c] - m - logS);
            }
            qlogq = s_ql;
        }
#pragma unroll
        for (int j = 1; j < 4; ++j) {
            const float* r = &lds[cur][j][t * 7];
            float z[7];
            float m = -1e30f;
#pragma unroll
            for (int c = 0; c < 7; ++c) {
                z[c] = r[c] * cst.invT[c];
                m = fmaxf(m, z[c]);
            }
            float S = 0.0f, dot = 0.0f;
#pragma unroll
            for (int c = 0; c < 7; ++c) {
                S   += __expf(z[c] - m);
                dot += q[c] * z[c];
            }
            cost_sum += qlogq - dot + m + __logf(S);
        }

        __syncthreads();   // buffer (cur^1) now complete; safe to overwrite cur
    }

    cost_sum *= (1.0f / 7.0f);   // mean over C

    // wave(64) shuffle reduction -> per-block -> one atomic
#pragma unroll
    for (int off = 32; off > 0; off >>= 1)
        cost_sum += __shfl_down(cost_sum, off, 64);
    if (lane == 0) red[w] = cost_sum;
    __syncthreads();
    if (t == 0)
        atomicAdd(out, (red[0] + red[1] + red[2] + red[3]) * cst.scale);
}

extern "C" void kernel_launch(void* const* d_in, const int* in_sizes, int n_in,
                              void* d_out, int out_size, void* d_ws, size_t ws_size,
                              hipStream_t stream)
{
    const float* x1 = (const float*)d_in[0];
    const float* x2 = (const float*)d_in[1];
    const float* x3 = (const float*)d_in[2];
    const float* x4 = (const float*)d_in[3];
    // d_in[4] = targets: dead input, never read.

    const int N = in_sizes[0] / 7;   // 2097152

    RideConsts cst;
    {
        const double cls[7] = {705, 717, 281, 4772, 1982, 1290, 2524};
        double sum = 0.0;
        for (int c = 0; c < 7; ++c) sum += cls[c];
        double w[7], wmax = 0.0;
        for (int c = 0; c < 7; ++c) {
            const double p = cls[c] / sum;
            w[c] = 7.0 * p * 0.015 + 1.0 - 0.015;
            if (w[c] > wmax) wmax = w[c];
        }
        double mT2 = 0.0;
        for (int c = 0; c < 7; ++c) {
            const float T = (float)(1.5 * (w[c] / wmax));
            cst.invT[c] = 1.0f / T;
            mT2 += (double)T * (double)T;
        }
        mT2 /= 7.0;
        cst.scale = (float)(mT2 / (3.0 * (double)N));
    }

    hipMemsetAsync(d_out, 0, sizeof(float), stream);

    // N = 2097152 rows = 8192 chunks of 256 rows; 512 blocks x 16 chunks.
    const int totalChunks    = N / 256;
    const int grid           = 512;
    const int chunksPerBlock = totalChunks / grid;   // exact for this problem

    ride_kernel<<<grid, 256, 0, stream>>>(x1, x2, x3, x4, (float*)d_out,
                                          cst, chunksPerBlock);
}